// Round 2
// baseline (136305.505 us; speedup 1.0000x reference)
//
#include <hip/hip_runtime.h>
#include <hip/hip_cooperative_groups.h>

namespace cg = cooperative_groups;

// Problem constants (match reference)
constexpr int Bsz  = 256;   // batch
constexpr int Lf   = 14;    // input features
constexpr int Tt   = 500;   // timesteps
constexpr int Hn   = 1000;  // hidden per layer
constexpr int HT   = 4;     // h-rows per block
constexpr int NBLK = Hn / HT;   // 250 blocks
constexpr int KPAD = 1024;      // padded k extent for bit words
constexpr int NWG  = Bsz / 64;  // 4 wave-groups (b-groups of 64)

// Spike bit buffers in d_ws:
//   layout [slot:2][layer:3][wgrp:4][KPAD] of u64
//   word (slot,layer,wg,k) = spike bits of neuron k for batches wg*64..wg*64+63
__device__ __forceinline__ size_t sb_off(int slot, int layer, int wg) {
  return (((size_t)slot * 3 + layer) * NWG + wg) * KPAD;
}

// Wave-uniform u64 (in VGPRs from a broadcast load) -> lane's own bit as 0.0/1.0.
// readfirstlane guarantees SGPR class for the asm "s" operands; mask goes via vcc.
__device__ __forceinline__ float sel01(unsigned long long w) {
  unsigned lo = __builtin_amdgcn_readfirstlane((unsigned)w);
  unsigned hi = __builtin_amdgcn_readfirstlane((unsigned)(w >> 32));
  float r;
  asm("s_mov_b32 vcc_lo, %1\n\t"
      "s_mov_b32 vcc_hi, %2\n\t"
      "v_cndmask_b32 %0, 0, 1.0, vcc"
      : "=v"(r) : "s"(lo), "s"(hi) : "vcc");
  return r;
}

// acc[j] += sum_k bit(b,k) * wrow[j*Hn + k]
// Spike words: uniform-address vector loads (broadcast). Weights: uniform
// const loads (compiler may scalarize - safe, weights immutable).
__device__ __forceinline__ void accum_bits(float acc[HT],
    const unsigned long long* __restrict__ bits,
    const float* __restrict__ wrow) {
  for (int kc = 0; kc < Hn; kc += 8) {   // 125 chunks of 8 k
    ulonglong2 m0 = *(const ulonglong2*)(bits + kc);
    ulonglong2 m1 = *(const ulonglong2*)(bits + kc + 2);
    ulonglong2 m2 = *(const ulonglong2*)(bits + kc + 4);
    ulonglong2 m3 = *(const ulonglong2*)(bits + kc + 6);
    float4 w0[HT], w1[HT];
#pragma unroll
    for (int j = 0; j < HT; ++j) {
      w0[j] = *(const float4*)(wrow + (size_t)j * Hn + kc);
      w1[j] = *(const float4*)(wrow + (size_t)j * Hn + kc + 4);
    }
    const float s0 = sel01(m0.x), s1 = sel01(m0.y);
    const float s2 = sel01(m1.x), s3 = sel01(m1.y);
    const float s4 = sel01(m2.x), s5 = sel01(m2.y);
    const float s6 = sel01(m3.x), s7 = sel01(m3.y);
#pragma unroll
    for (int j = 0; j < HT; ++j) {
      acc[j] = fmaf(w0[j].x, s0, acc[j]);
      acc[j] = fmaf(w0[j].y, s1, acc[j]);
      acc[j] = fmaf(w0[j].z, s2, acc[j]);
      acc[j] = fmaf(w0[j].w, s3, acc[j]);
      acc[j] = fmaf(w1[j].x, s4, acc[j]);
      acc[j] = fmaf(w1[j].y, s5, acc[j]);
      acc[j] = fmaf(w1[j].z, s6, acc[j]);
      acc[j] = fmaf(w1[j].w, s7, acc[j]);
    }
  }
}

// LIF update (tau=2, v_th=1, hard reset to 0) + ballot spikes into bit buffer
__device__ __forceinline__ void lif_store(float v[HT], const float acc[HT],
    unsigned long long* __restrict__ sbout, int h0, int lane) {
#pragma unroll
  for (int j = 0; j < HT; ++j) {
    float vn = v[j] + (acc[j] - v[j]) * 0.5f;  // v += (h - v)/tau
    bool sp = (vn >= 1.0f);
    unsigned long long m = __ballot(sp);
    v[j] = sp ? 0.0f : vn;
    if (lane == 0) sbout[h0 + j] = m;
  }
}

__global__ void __launch_bounds__(256, 1)
snn_coop(const float* __restrict__ x,
         const float* __restrict__ W1, const float* __restrict__ R1,
         const float* __restrict__ W2, const float* __restrict__ R2,
         const float* __restrict__ W3, const float* __restrict__ R3,
         unsigned long long* __restrict__ sb,
         float* __restrict__ out)
{
  cg::grid_group grid = cg::this_grid();
  const int tid  = threadIdx.x;
  const int lane = tid & 63;
  const int wg   = __builtin_amdgcn_readfirstlane(tid >> 6); // b-group 0..3
  const int b    = tid;                                      // batch index
  const int h0   = blockIdx.x * HT;                          // uniform

  const float* W1r = W1 + (size_t)h0 * Lf;
  const float* R1r = R1 + (size_t)h0 * Hn;
  const float* W2r = W2 + (size_t)h0 * Hn;
  const float* R2r = R2 + (size_t)h0 * Hn;
  const float* W3r = W3 + (size_t)h0 * Hn;
  const float* R3r = R3 + (size_t)h0 * Hn;

  float v1[HT], v2[HT], v3[HT];
#pragma unroll
  for (int j = 0; j < HT; ++j) { v1[j] = 0.0f; v2[j] = 0.0f; v3[j] = 0.0f; }

  const float* xb = x + (size_t)b * (Lf * Tt); // x[b][l][t]

  // Diagonal pipeline: phase p -> L1@t=p, L2@t=p-1, L3@t=p-2.
  // Writes in phase p go to slot (p&1); reads come from slot ((p-1)&1).
  for (int p = 0; p < Tt + 2; ++p) {
    const int srd = (p + 1) & 1;
    const int swr = p & 1;

    if (p < Tt) {  // ---- layer 1, t = p ----
      float acc[HT] = {0.f, 0.f, 0.f, 0.f};
#pragma unroll
      for (int l = 0; l < Lf; ++l) {
        float xv = xb[(size_t)l * Tt + p];
#pragma unroll
        for (int j = 0; j < HT; ++j)
          acc[j] = fmaf(W1r[j * Lf + l], xv, acc[j]);
      }
      accum_bits(acc, sb + sb_off(srd, 0, wg), R1r);         // c1 @ R1^T
      lif_store(v1, acc, sb + sb_off(swr, 0, wg), h0, lane);
    }

    if (p >= 1 && p <= Tt) {  // ---- layer 2, t = p-1 ----
      float acc[HT] = {0.f, 0.f, 0.f, 0.f};
      accum_bits(acc, sb + sb_off(srd, 0, wg), W2r);         // s1(t) @ W2^T
      accum_bits(acc, sb + sb_off(srd, 1, wg), R2r);         // c2 @ R2^T
      lif_store(v2, acc, sb + sb_off(swr, 1, wg), h0, lane);
    }

    if (p >= 2) {  // ---- layer 3, t = p-2 ----
      float acc[HT] = {0.f, 0.f, 0.f, 0.f};
      accum_bits(acc, sb + sb_off(srd, 1, wg), W3r);         // s2(t) @ W3^T
      accum_bits(acc, sb + sb_off(srd, 2, wg), R3r);         // c3 @ R3^T
      lif_store(v3, acc, sb + sb_off(swr, 2, wg), h0, lane);
    }

    __threadfence();   // make spike stores visible device-wide (cross-XCD)
    grid.sync();
  }

  // Output: exp(final v3), [B][H] row-major
#pragma unroll
  for (int j = 0; j < HT; ++j)
    out[(size_t)b * Hn + h0 + j] = expf(v3[j]);
}

extern "C" void kernel_launch(void* const* d_in, const int* in_sizes, int n_in,
                              void* d_out, int out_size, void* d_ws, size_t ws_size,
                              hipStream_t stream) {
  const float* x  = (const float*)d_in[0];
  const float* W1 = (const float*)d_in[1];
  const float* R1 = (const float*)d_in[2];
  const float* W2 = (const float*)d_in[3];
  const float* R2 = (const float*)d_in[4];
  const float* W3 = (const float*)d_in[5];
  const float* R3 = (const float*)d_in[6];
  float* out = (float*)d_out;

  unsigned long long* sbits = (unsigned long long*)d_ws;
  const size_t sb_bytes = (size_t)2 * 3 * NWG * KPAD * sizeof(unsigned long long); // 196608 B

  // zero both spike-slot buffers (initial carries are zero)
  hipMemsetAsync(d_ws, 0, sb_bytes, stream);

  void* args[] = { (void*)&x, (void*)&W1, (void*)&R1, (void*)&W2, (void*)&R2,
                   (void*)&W3, (void*)&R3, (void*)&sbits, (void*)&out };
  hipLaunchCooperativeKernel((const void*)snn_coop, dim3(NBLK), dim3(256),
                             args, 0, stream);
}

// Round 3
// 98001.373 us; speedup vs baseline: 1.3909x; 1.3909x over previous
//
#include <hip/hip_runtime.h>
#include <hip/hip_cooperative_groups.h>

namespace cg = cooperative_groups;

// Problem constants (match reference)
constexpr int Bsz  = 256;   // batch
constexpr int Lf   = 14;    // input features
constexpr int Tt   = 500;   // timesteps
constexpr int Hn   = 1000;  // hidden per layer
constexpr int HT   = 4;     // h-rows per block
constexpr int NBLK = Hn / HT;   // 250 blocks
constexpr int KPAD = 1024;      // spike row stride in bytes
constexpr int NKS  = 4;         // k-splits (block = NKS * 256 threads)

// Spike byte buffers in d_ws: [slot:2][layer:3][b:256][KPAD] u8 (1.5 MB)
// byte (slot,layer,b,k) = spike of neuron k, batch b (0 or 1)
__device__ __forceinline__ size_t srow_off(int slot, int layer, int b) {
  return (((size_t)slot * 3 + layer) * Bsz + b) * KPAD;
}

// 4 bytes of a dword -> 4 floats (0.0/1.0); selects v_cvt_f32_ubyte0..3
__device__ __forceinline__ void cvt4(unsigned w, float* s) {
  s[0] = (float)(w & 0xffu);
  s[1] = (float)((w >> 8) & 0xffu);
  s[2] = (float)((w >> 16) & 0xffu);
  s[3] = (float)(w >> 24);
}

// acc[j] += sum_{k in [k0,k1)} spike(b,k) * wrow[j*Hn + k]
// srow: per-lane spike row base (this lane's b). wrow: uniform weight rows.
// (k1-k0) is a multiple of 8; main loop 16-wide, tail 8-wide.
__device__ __forceinline__ void accum_range(float acc[HT],
    const unsigned char* __restrict__ srow,
    const float* __restrict__ wrow, int k0, int k1) {
  int kc = k0;
  for (; kc + 16 <= k1; kc += 16) {
    uint4 sw = *(const uint4*)(srow + kc);
    float s[16];
    cvt4(sw.x, s); cvt4(sw.y, s + 4); cvt4(sw.z, s + 8); cvt4(sw.w, s + 12);
#pragma unroll
    for (int j = 0; j < HT; ++j) {
      const float* wr = wrow + (size_t)j * Hn + kc;
      float4 wa = *(const float4*)(wr);
      float4 wb = *(const float4*)(wr + 4);
      float4 wc = *(const float4*)(wr + 8);
      float4 wd = *(const float4*)(wr + 12);
      acc[j] = fmaf(wa.x, s[0],  acc[j]);
      acc[j] = fmaf(wa.y, s[1],  acc[j]);
      acc[j] = fmaf(wa.z, s[2],  acc[j]);
      acc[j] = fmaf(wa.w, s[3],  acc[j]);
      acc[j] = fmaf(wb.x, s[4],  acc[j]);
      acc[j] = fmaf(wb.y, s[5],  acc[j]);
      acc[j] = fmaf(wb.z, s[6],  acc[j]);
      acc[j] = fmaf(wb.w, s[7],  acc[j]);
      acc[j] = fmaf(wc.x, s[8],  acc[j]);
      acc[j] = fmaf(wc.y, s[9],  acc[j]);
      acc[j] = fmaf(wc.z, s[10], acc[j]);
      acc[j] = fmaf(wc.w, s[11], acc[j]);
      acc[j] = fmaf(wd.x, s[12], acc[j]);
      acc[j] = fmaf(wd.y, s[13], acc[j]);
      acc[j] = fmaf(wd.z, s[14], acc[j]);
      acc[j] = fmaf(wd.w, s[15], acc[j]);
    }
  }
  if (kc < k1) {  // 8-wide tail
    uint2 sw = *(const uint2*)(srow + kc);
    float s[8];
    cvt4(sw.x, s); cvt4(sw.y, s + 4);
#pragma unroll
    for (int j = 0; j < HT; ++j) {
      const float* wr = wrow + (size_t)j * Hn + kc;
      float4 wa = *(const float4*)(wr);
      float4 wb = *(const float4*)(wr + 4);
      acc[j] = fmaf(wa.x, s[0], acc[j]);
      acc[j] = fmaf(wa.y, s[1], acc[j]);
      acc[j] = fmaf(wa.z, s[2], acc[j]);
      acc[j] = fmaf(wa.w, s[3], acc[j]);
      acc[j] = fmaf(wb.x, s[4], acc[j]);
      acc[j] = fmaf(wb.y, s[5], acc[j]);
      acc[j] = fmaf(wb.z, s[6], acc[j]);
      acc[j] = fmaf(wb.w, s[7], acc[j]);
    }
  }
}

// LIF (tau=2, v_th=1, hard reset) for 4 neurons; returns packed spike bytes
__device__ __forceinline__ unsigned lif_pack(float v[HT], const float a[HT]) {
  unsigned pack = 0;
#pragma unroll
  for (int j = 0; j < HT; ++j) {
    float vn = v[j] + (a[j] - v[j]) * 0.5f;
    bool sp = (vn >= 1.0f);
    v[j] = sp ? 0.0f : vn;
    pack |= (sp ? 1u : 0u) << (8 * j);
  }
  return pack;
}

__global__ void __launch_bounds__(1024, 4)
snn_coop(const float* __restrict__ x,
         const float* __restrict__ W1, const float* __restrict__ R1,
         const float* __restrict__ W2, const float* __restrict__ R2,
         const float* __restrict__ W3, const float* __restrict__ R3,
         unsigned char* __restrict__ sb,
         float* __restrict__ out)
{
  cg::grid_group grid = cg::this_grid();
  const int tid = threadIdx.x;
  const int b   = tid & 255;                                  // batch
  const int ks  = __builtin_amdgcn_readfirstlane(tid >> 8);   // k-split 0..3
  const int h0  = blockIdx.x * HT;                            // uniform

  const int k0 = ks * 256;
  const int k1 = (ks == 3) ? Hn : (k0 + 256);   // 256/256/256/232

  const float* W1r = W1 + (size_t)h0 * Lf;
  const float* R1r = R1 + (size_t)h0 * Hn;
  const float* W2r = W2 + (size_t)h0 * Hn;
  const float* R2r = R2 + (size_t)h0 * Hn;
  const float* W3r = W3 + (size_t)h0 * Hn;
  const float* R3r = R3 + (size_t)h0 * Hn;

  // partial-sum exchange: [parity][layer][ks-1][b] (float4 = acc[4])
  __shared__ float4 red[2][3][NKS - 1][Bsz];   // 36 KB

  float v1[HT], v2[HT], v3[HT];
#pragma unroll
  for (int j = 0; j < HT; ++j) { v1[j] = 0.f; v2[j] = 0.f; v3[j] = 0.f; }

  const float* xb = x + (size_t)b * (Lf * Tt); // x[b][l][t]

  // Diagonal pipeline: phase p -> L1@t=p, L2@t=p-1, L3@t=p-2.
  // Spike writes in phase p go to slot (p&1); reads from slot ((p-1)&1).
  for (int p = 0; p < Tt + 2; ++p) {
    const int srd = (p + 1) & 1;
    const int swr = p & 1;

    float a1[HT] = {0.f, 0.f, 0.f, 0.f};
    float a2[HT] = {0.f, 0.f, 0.f, 0.f};
    float a3[HT] = {0.f, 0.f, 0.f, 0.f};

    const bool l1on = (p < Tt);
    const bool l2on = (p >= 1) && (p <= Tt);
    const bool l3on = (p >= 2);

    if (l1on) {
      if (ks == 3) {   // feedforward x @ W1^T (k=14), lighter k-split wave
#pragma unroll
        for (int l = 0; l < Lf; ++l) {
          float xv = xb[(size_t)l * Tt + p];
#pragma unroll
          for (int j = 0; j < HT; ++j)
            a1[j] = fmaf(W1r[j * Lf + l], xv, a1[j]);
        }
      }
      accum_range(a1, sb + srow_off(srd, 0, b), R1r, k0, k1);   // c1 @ R1^T
    }
    if (l2on) {
      accum_range(a2, sb + srow_off(srd, 0, b), W2r, k0, k1);   // s1 @ W2^T
      accum_range(a2, sb + srow_off(srd, 1, b), R2r, k0, k1);   // c2 @ R2^T
    }
    if (l3on) {
      accum_range(a3, sb + srow_off(srd, 1, b), W3r, k0, k1);   // s2 @ W3^T
      accum_range(a3, sb + srow_off(srd, 2, b), R3r, k0, k1);   // c3 @ R3^T
    }

    if (ks != 0) {
      if (l1on) red[swr][0][ks - 1][b] = make_float4(a1[0], a1[1], a1[2], a1[3]);
      if (l2on) red[swr][1][ks - 1][b] = make_float4(a2[0], a2[1], a2[2], a2[3]);
      if (l3on) red[swr][2][ks - 1][b] = make_float4(a3[0], a3[1], a3[2], a3[3]);
    }
    __syncthreads();

    if (ks == 0) {
      if (l1on) {
#pragma unroll
        for (int q = 0; q < NKS - 1; ++q) {
          float4 r = red[swr][0][q][b];
          a1[0] += r.x; a1[1] += r.y; a1[2] += r.z; a1[3] += r.w;
        }
        unsigned pk = lif_pack(v1, a1);
        *(unsigned*)(sb + srow_off(swr, 0, b) + h0) = pk;
      }
      if (l2on) {
#pragma unroll
        for (int q = 0; q < NKS - 1; ++q) {
          float4 r = red[swr][1][q][b];
          a2[0] += r.x; a2[1] += r.y; a2[2] += r.z; a2[3] += r.w;
        }
        unsigned pk = lif_pack(v2, a2);
        *(unsigned*)(sb + srow_off(swr, 1, b) + h0) = pk;
      }
      if (l3on) {
#pragma unroll
        for (int q = 0; q < NKS - 1; ++q) {
          float4 r = red[swr][2][q][b];
          a3[0] += r.x; a3[1] += r.y; a3[2] += r.z; a3[3] += r.w;
        }
        unsigned pk = lif_pack(v3, a3);
        *(unsigned*)(sb + srow_off(swr, 2, b) + h0) = pk;
      }
    }

    __threadfence();   // spike stores visible device-wide before next phase
    grid.sync();
  }

  // Output: exp(final v3) from ks==0 threads; [B][H] row-major, float4 store
  if (ks == 0) {
    float4 o = make_float4(expf(v3[0]), expf(v3[1]), expf(v3[2]), expf(v3[3]));
    *(float4*)(out + (size_t)b * Hn + h0) = o;
  }
}

extern "C" void kernel_launch(void* const* d_in, const int* in_sizes, int n_in,
                              void* d_out, int out_size, void* d_ws, size_t ws_size,
                              hipStream_t stream) {
  const float* x  = (const float*)d_in[0];
  const float* W1 = (const float*)d_in[1];
  const float* R1 = (const float*)d_in[2];
  const float* W2 = (const float*)d_in[3];
  const float* R2 = (const float*)d_in[4];
  const float* W3 = (const float*)d_in[5];
  const float* R3 = (const float*)d_in[6];
  float* out = (float*)d_out;

  unsigned char* sbytes = (unsigned char*)d_ws;
  const size_t sb_bytes = (size_t)2 * 3 * Bsz * KPAD; // 1,572,864 B

  // zero both spike slots (initial carries are zero)
  hipMemsetAsync(d_ws, 0, sb_bytes, stream);

  void* args[] = { (void*)&x, (void*)&W1, (void*)&R1, (void*)&W2, (void*)&R2,
                   (void*)&W3, (void*)&R3, (void*)&sbytes, (void*)&out };
  hipLaunchCooperativeKernel((const void*)snn_coop, dim3(NBLK), dim3(1024),
                             args, 0, stream);
}